// Round 6
// baseline (130.778 us; speedup 1.0000x reference)
//
#include <hip/hip_runtime.h>
#include <hip/hip_bf16.h>
#include <math.h>

// Problem constants
#define MM 12544   // 64 * 196 patches
#define KK 768     // 16*16*3
#define NN 768     // embedding dim
#define BM 64
#define BN 256
#define BK 64
#define KT 12              // KK/BK
#define MT 196             // MM/BM
#define NT 3               // NN/BN
#define TILE_B_BYTES (BN*BK*2)   // 32768

#define WTPACK_BLOCKS ((NN * 96) / 256)   // 288

typedef __bf16 v8bf __attribute__((ext_vector_type(8)));
typedef float  v4f  __attribute__((ext_vector_type(4)));

// ---------------------------------------------------------------------------
// W-pack: W [k][n] fp32 -> [nt][kt][n 0..255][g^(n&7)][8] bf16. ~1.5 us.
// ---------------------------------------------------------------------------
__global__ __launch_bounds__(256) void wt_pack(const float* __restrict__ w,
                                               __hip_bfloat16* __restrict__ wpack) {
    int tid = blockIdx.x * 256 + threadIdx.x;   // 0 .. 768*96-1
    int n   = tid % 768;
    int gg  = tid / 768;
    int k0  = gg * 8;
    float f[8];
#pragma unroll
    for (int j = 0; j < 8; j++) f[j] = w[(size_t)(k0 + j) * NN + n];
    int nt = n >> 8;
    int nr = n & 255;
    int kt = gg >> 3;
    int g  = gg & 7;
    int gs = g ^ (nr & 7);
    union { __hip_bfloat16 h[8]; uint4 u; } o;
#pragma unroll
    for (int j = 0; j < 8; j++) o.h[j] = __float2bfloat16(f[j]);
    *(uint4*)(wpack + ((size_t)(nt * KT + kt) * BN + nr) * BK + gs * 8) = o.u;
}

// Fast GELU: x*E/(E+1), E=e^{2t}, t=0.79788456(x+0.044715x^3).
__device__ __forceinline__ float gelu_fast(float x) {
    float t2 = 1.5957691216057308f * x * (1.0f + 0.044715f * x * x);
    float e  = __expf(t2);
    float r  = __builtin_amdgcn_rcpf(e + 1.0f);
    return x - x * r;
}

// ---------------------------------------------------------------------------
// Fused im2col + bf16 MFMA GEMM + bias + GELU — SOFTWARE-PIPELINED K-loop.
// Double-buffered As (2x8KB) and Bs (2x32KB), ONE barrier per iter.
// Iter body order: issue B(kt+1) global_load_lds + A(kt+1) image loads
// FIRST (no waits), then all 32 MFMAs on current buffers (no vmem dep),
// then cvt+ds_write A(kt+1) (vmcnt wait lands after the MFMA block).
// Barrier drains vmcnt(0)+lgkmcnt(0), validating the NEXT iter's buffers.
// ---------------------------------------------------------------------------
__global__ __launch_bounds__(256, 2) void gemm_gelu(const float* __restrict__ img,
                                                    const __hip_bfloat16* __restrict__ wpack,
                                                    const float* __restrict__ bias,
                                                    float* __restrict__ out) {
    __shared__ __align__(16) __hip_bfloat16 As[2 * BM * BK];   // 2 x  8 KB
    __shared__ __align__(16) __hip_bfloat16 Bs[2 * BN * BK];   // 2 x 32 KB

    const int blk = blockIdx.x;
    const int nt  = blk % 3;
    const int mt  = blk / 3;

    const int tid  = threadIdx.x;
    const int lane = tid & 63;
    const int wave = tid >> 6;
    const int wn   = wave * 64;
    const int col  = lane & 15;
    const int quad = lane >> 4;
    const int cl7  = col & 7;

    // --- per-thread im2col geometry ---
    const int r = tid >> 2;              // A row within tile = patch offset
    const int q = tid & 3;               // k-subrange [q*16, q*16+16)
    unsigned m  = (unsigned)(mt * BM + r);
    unsigned b  = m / 196u;
    unsigned pm = m - b * 196u;
    unsigned pr = pm / 14u;
    unsigned pc = pm - pr * 14u;
    const float* pbase = img + (size_t)(((b * 224u + pr * 16u) * 224u + pc * 16u) * 3u);
    const int gs0 = (2 * q) ^ (r & 7);
    const int gs1 = gs0 ^ 1;

    v4f acc[4][4];
    const v4f vzero = {0.f, 0.f, 0.f, 0.f};
#pragma unroll
    for (int a = 0; a < 4; a++)
#pragma unroll
        for (int c = 0; c < 4; c++) acc[a][c] = vzero;

    const char* bT = (const char*)wpack + (size_t)nt * KT * TILE_B_BYTES;

    // ================= prologue: stage kt=0 =================
#pragma unroll
    for (int p = 0; p < 8; p++) {
        int off = p * 4096 + tid * 16;
        __builtin_amdgcn_global_load_lds(
            (const __attribute__((address_space(1))) void*)(bT + off),
            (__attribute__((address_space(3))) void*)((char*)Bs + off), 16, 0, 0);
    }
    {
        float4 f4[4];
#pragma unroll
        for (int j = 0; j < 4; j++) {
            unsigned k   = (unsigned)(q * 16 + j * 4);
            unsigned i   = k / 48u;
            unsigned rem = k - i * 48u;
            f4[j] = *(const float4*)(pbase + i * 672u + rem);
        }
        union { __hip_bfloat16 h[8]; uint4 u; } lo, hi;
        lo.h[0] = __float2bfloat16(f4[0].x); lo.h[1] = __float2bfloat16(f4[0].y);
        lo.h[2] = __float2bfloat16(f4[0].z); lo.h[3] = __float2bfloat16(f4[0].w);
        lo.h[4] = __float2bfloat16(f4[1].x); lo.h[5] = __float2bfloat16(f4[1].y);
        lo.h[6] = __float2bfloat16(f4[1].z); lo.h[7] = __float2bfloat16(f4[1].w);
        hi.h[0] = __float2bfloat16(f4[2].x); hi.h[1] = __float2bfloat16(f4[2].y);
        hi.h[2] = __float2bfloat16(f4[2].z); hi.h[3] = __float2bfloat16(f4[2].w);
        hi.h[4] = __float2bfloat16(f4[3].x); hi.h[5] = __float2bfloat16(f4[3].y);
        hi.h[6] = __float2bfloat16(f4[3].z); hi.h[7] = __float2bfloat16(f4[3].w);
        uint4* As16 = (uint4*)As;
        As16[r * 8 + gs0] = lo.u;
        As16[r * 8 + gs1] = hi.u;
    }
    __syncthreads();

    // ================= pipelined main loop =================
    for (int kt = 0; kt < KT; kt++) {
        const int cur = kt & 1;
        const __hip_bfloat16* Asc = As + cur * (BM * BK);
        const __hip_bfloat16* Bsc = Bs + cur * (BN * BK);

        float4 f4[4];
        const bool more = (kt + 1 < KT);
        if (more) {
            // --- issue next B tile into alternate buffer (async) ---
            const char* bN  = bT + (size_t)(kt + 1) * TILE_B_BYTES;
            char*       BsN = (char*)(Bs + (cur ^ 1) * (BN * BK));
#pragma unroll
            for (int p = 0; p < 8; p++) {
                int off = p * 4096 + tid * 16;
                __builtin_amdgcn_global_load_lds(
                    (const __attribute__((address_space(1))) void*)(bN + off),
                    (__attribute__((address_space(3))) void*)(BsN + off), 16, 0, 0);
            }
            // --- issue next A image loads into VGPRs (no wait yet) ---
#pragma unroll
            for (int j = 0; j < 4; j++) {
                unsigned k   = (unsigned)((kt + 1) * 64 + q * 16 + j * 4);
                unsigned i   = k / 48u;
                unsigned rem = k - i * 48u;
                f4[j] = *(const float4*)(pbase + i * 672u + rem);
            }
        }

        // --- compute on current buffers: no vmem dependency ---
#pragma unroll
        for (int ks = 0; ks < 2; ks++) {
            const int gs = (ks * 4 + quad) ^ cl7;
            const v8bf* pa = (const v8bf*)(Asc + col * BK + gs * 8);
            const v8bf* pb = (const v8bf*)(Bsc + (wn + col) * BK + gs * 8);
            v8bf af[4], bfr[4];
#pragma unroll
            for (int mi = 0; mi < 4; mi++) af[mi] = pa[mi * 128];
#pragma unroll
            for (int ni = 0; ni < 4; ni++) bfr[ni] = pb[ni * 128];
#pragma unroll
            for (int mi = 0; mi < 4; mi++)
#pragma unroll
                for (int ni = 0; ni < 4; ni++)
                    acc[mi][ni] = __builtin_amdgcn_mfma_f32_16x16x32_bf16(
                        af[mi], bfr[ni], acc[mi][ni], 0, 0, 0);
        }

        if (more) {
            // --- cvt + write next A into alternate buffer ---
            union { __hip_bfloat16 h[8]; uint4 u; } lo, hi;
            lo.h[0] = __float2bfloat16(f4[0].x); lo.h[1] = __float2bfloat16(f4[0].y);
            lo.h[2] = __float2bfloat16(f4[0].z); lo.h[3] = __float2bfloat16(f4[0].w);
            lo.h[4] = __float2bfloat16(f4[1].x); lo.h[5] = __float2bfloat16(f4[1].y);
            lo.h[6] = __float2bfloat16(f4[1].z); lo.h[7] = __float2bfloat16(f4[1].w);
            hi.h[0] = __float2bfloat16(f4[2].x); hi.h[1] = __float2bfloat16(f4[2].y);
            hi.h[2] = __float2bfloat16(f4[2].z); hi.h[3] = __float2bfloat16(f4[2].w);
            hi.h[4] = __float2bfloat16(f4[3].x); hi.h[5] = __float2bfloat16(f4[3].y);
            hi.h[6] = __float2bfloat16(f4[3].z); hi.h[7] = __float2bfloat16(f4[3].w);
            uint4* AsN = (uint4*)(As + (cur ^ 1) * (BM * BK));
            AsN[r * 8 + gs0] = lo.u;
            AsN[r * 8 + gs1] = hi.u;
        }
        __syncthreads();
    }

    // ---- epilogue: bias + fast GELU, coalesced fp32 stores ----
#pragma unroll
    for (int ni = 0; ni < 4; ni++) {
        int n    = nt * BN + wn + ni * 16 + col;
        float bv = bias[n];
#pragma unroll
        for (int mi = 0; mi < 4; mi++) {
            int rowb = mt * BM + mi * 16 + quad * 4;
            float* po = out + (size_t)rowb * NN + n;
#pragma unroll
            for (int rg = 0; rg < 4; rg++) {
                float x = acc[mi][ni][rg] + bv;
                po[(size_t)rg * NN] = gelu_fast(x);
            }
        }
    }
}

extern "C" void kernel_launch(void* const* d_in, const int* in_sizes, int n_in,
                              void* d_out, int out_size, void* d_ws, size_t ws_size,
                              hipStream_t stream) {
    const float* img   = (const float*)d_in[0];   // [64,224,224,3]
    const float* wproj = (const float*)d_in[1];   // [768,768]
    const float* bias  = (const float*)d_in[2];   // [768]
    float* out = (float*)d_out;                   // [64,196,768]

    __hip_bfloat16* wpack = (__hip_bfloat16*)d_ws;   // 1,179,648 B used

    wt_pack<<<dim3(WTPACK_BLOCKS), dim3(256), 0, stream>>>(wproj, wpack);
    gemm_gelu<<<dim3(MT * NT), dim3(256), 0, stream>>>(img, wpack, bias, out);
}